// Round 12
// baseline (1492.943 us; speedup 1.0000x reference)
//
#include <hip/hip_runtime.h>
#include <hip/hip_bf16.h>
#include <cstddef>

#define HH 48
#define WW 48
#define PIX 2304
#define PPIX 2704           // 52*52 padded
#define BB 128
#define RESC 128
#define XCH 33

typedef short bf16x8 __attribute__((ext_vector_type(8)));
typedef float f32x4 __attribute__((ext_vector_type(4)));

static __device__ __forceinline__ float b2f(unsigned short u) {
    unsigned x = ((unsigned)u) << 16;
    return __builtin_bit_cast(float, x);
}
static __device__ __forceinline__ unsigned short f2b(float f) {
    __hip_bfloat16 hb = __float2bfloat16(f);
    return __builtin_bit_cast(unsigned short, hb);
}

#define GLOAD_LDS16(gp, lp) __builtin_amdgcn_global_load_lds( \
    (const __attribute__((address_space(1))) void*)(gp), \
    (__attribute__((address_space(3))) void*)(lp), 16, 0, 0)

// ---------------- K1: one-hot gather -> v[128][9] ----------------
__global__ void k_compute_v(const float* __restrict__ x, const float* __restrict__ fc_w,
                            const float* __restrict__ fc_b, float* __restrict__ v) {
    int b = blockIdx.x * blockDim.x + threadIdx.x;
    if (b >= BB) return;
    const int off[20] = {0,5,12,16,22,25,33,38,42,48,55,58,63,67,73,81,86,93,97,103};
    const float* gi = x + (size_t)b * XCH * PIX;
    int cols[20];
    #pragma unroll
    for (int j = 0; j < 20; j++) cols[j] = off[j] + (int)gi[j];
    #pragma unroll
    for (int e = 0; e < 9; e++) {
        float acc = fc_b[e];
        #pragma unroll
        for (int j = 0; j < 20; j++) acc += fc_w[e * 106 + cols[j]];
        v[b * 9 + e] = acc;
    }
}

// ---------------- K2: per-pixel composite G[p][128oc] fp32 ----------------
__global__ void k_compute_G(const float* __restrict__ x, const float* __restrict__ v,
                            const float* __restrict__ ohw, const float* __restrict__ ohb,
                            const float* __restrict__ otw, const float* __restrict__ otb,
                            const float* __restrict__ aw,  const float* __restrict__ ab,
                            const float* __restrict__ c1w, const float* __restrict__ c1b,
                            float* __restrict__ G) {
    int p = blockIdx.x * blockDim.x + threadIdx.x;
    if (p >= PIX) return;
    float sv = v[((p / 9) & 127) * 9 + (p % 9)];
    float om[30];
    #pragma unroll
    for (int c2 = 0; c2 < 30; c2++) {
        int tmp = c2 * 24 + p;
        int c = tmp % 30;
        int bb = (c2 * 76 + tmp / 30) & 127;
        om[c2] = x[(size_t)bb * XCH * PIX + 20 + c];
    }
    float v9[9];
    #pragma unroll
    for (int e = 0; e < 9; e++) {
        float srow = 0.f;
        #pragma unroll
        for (int e2 = 0; e2 < 9; e2++) srow += ohw[e * 9 + e2];
        v9[e] = ohb[e] + srow * sv;
    }
    float o30[30];
    #pragma unroll
    for (int c = 0; c < 30; c++) {
        float a = otb[c];
        #pragma unroll
        for (int c2 = 0; c2 < 30; c2++) a += otw[c * 30 + c2] * om[c2];
        o30[c] = a;
    }
    float gi32[32];
    #pragma unroll
    for (int g = 0; g < 32; g++) {
        float a = ab[g];
        #pragma unroll
        for (int e = 0; e < 9; e++) a += aw[g * 39 + e] * v9[e];
        #pragma unroll
        for (int c = 0; c < 30; c++) a += aw[g * 39 + 9 + c] * o30[c];
        gi32[g] = a;
    }
    for (int oc = 0; oc < 128; oc++) {
        float a = c1b[oc];
        #pragma unroll
        for (int g = 0; g < 32; g++) a += c1w[oc * 64 + g] * gi32[g];
        G[p * 128 + oc] = a;
    }
}

// ---------------- K2b: weights -> bf16 [tap][oc][ic] ----------------
__global__ void k_convert_w(const float* __restrict__ w1, const float* __restrict__ w2,
                            __hip_bfloat16* __restrict__ wb1, __hip_bfloat16* __restrict__ wb2) {
    int i = blockIdx.x * 256 + threadIdx.x;
    if (i >= 25 * 128 * 128) return;
    int tap = i / 16384, r = i % 16384;
    int oc = r >> 7, ic = r & 127;
    size_t src = (size_t)(oc * 128 + ic) * 25 + tap;
    wb1[i] = __float2bfloat16(w1[src]);
    wb2[i] = __float2bfloat16(w2[src]);
}

// ---------------- K2c: zero borders of the two padded buffers ----------------
__global__ void k_zero_border(__hip_bfloat16* __restrict__ a, __hip_bfloat16* __restrict__ b2) {
    int img = blockIdx.x, t = threadIdx.x;
    for (int j = t; j < 6400; j += 256) {
        int pb = j >> 4, c16 = j & 15;
        int y, x2;
        if (pb < 208) { int q = pb / 52; y = q < 2 ? q : q + 48; x2 = pb % 52; }
        else { int r = pb - 208; y = 2 + (r >> 2); int c = r & 3; x2 = c < 2 ? c : c + 48; }
        size_t off = ((size_t)img * PPIX + y * 52 + x2) * 128 + c16 * 8;
        uint4 z = {0, 0, 0, 0};
        *(uint4*)(a + off) = z;
        *(uint4*)(b2 + off) = z;
    }
}

// ---------------- K3: h_pad[b][52][52][128] = G + W1[:,32:] @ map ----------------
__global__ __launch_bounds__(256) void k_conv1(const float* __restrict__ x, const float* __restrict__ c1w,
                                               const float* __restrict__ G, __hip_bfloat16* __restrict__ h) {
    __shared__ float xm[32][64];
    __shared__ float w1[32][128];
    int b = blockIdx.y, p0 = blockIdx.x * 64;
    int t = threadIdx.x;
    for (int i = t; i < 4096; i += 256) { int m = i >> 7, oc = i & 127; w1[m][oc] = c1w[oc * 64 + 32 + m]; }
    for (int i = t; i < 2048; i += 256) {
        int m = i >> 6, pix = i & 63;
        xm[m][pix] = x[(size_t)b * XCH * PIX + (size_t)(1 + m) * PIX + p0 + pix];
    }
    __syncthreads();
    int pix = t & 63, ocg = t >> 6;
    float acc[32] = {};
    for (int m = 0; m < 32; m++) {
        float xv = xm[m][pix];
        const float4* wr = (const float4*)&w1[m][ocg * 32];
        #pragma unroll
        for (int k4 = 0; k4 < 8; k4++) {
            float4 wv = wr[k4];
            acc[k4 * 4 + 0] += wv.x * xv; acc[k4 * 4 + 1] += wv.y * xv;
            acc[k4 * 4 + 2] += wv.z * xv; acc[k4 * 4 + 3] += wv.w * xv;
        }
    }
    int p = p0 + pix;
    int py = p / 48, px2 = p % 48;
    size_t hb = ((size_t)b * PPIX + (py + 2) * 52 + px2 + 2) * 128 + ocg * 32;
    const float* gp = &G[(size_t)p * 128 + ocg * 32];
    #pragma unroll
    for (int q = 0; q < 4; q++) {
        unsigned short u[8];
        #pragma unroll
        for (int j = 0; j < 8; j++) u[j] = f2b(acc[q * 8 + j] + gp[q * 8 + j]);
        *(uint4*)(&h[hb + q * 8]) = *(uint4*)u;
    }
}

// ---------------- K4/K5: 5x5 conv, implicit GEMM (R7 attractor + 8-wave occupancy) ----
// block: 1 batch, 16x16 spatial, 128 oc, 512 threads = 8 waves.
// wave (wm: oc-half, wq: row-quad) = 64oc x 64px: acc[4][4] = 64 AGPR.
// ~148 regs total -> 3 waves/SIMD (vs R7's 2). Same 1152-block grid, XCD swizzle,
// LDS layout, 7-part staged interleave, depth-2 A-prefetch — attractor preserved.
template<bool LEAKY, bool MEAN, bool PADOUT>
__global__ __launch_bounds__(512, 3) void k_conv5_mfma(
        const __hip_bfloat16* __restrict__ in,   // [B][52][52][128] padded
        const __hip_bfloat16* __restrict__ w,    // [25][128][128]
        const float* __restrict__ bias,
        __hip_bfloat16* __restrict__ out,
        float* __restrict__ mean) {
    __shared__ __align__(16) char lds[2][25600];
    // XCD-batch swizzle: 1152 blocks = 8 XCDs x (16 batches x 9 tiles)
    int bid = blockIdx.x;
    int xcd = bid & 7, loc = bid >> 3;
    int b = xcd * 16 + loc / 9;
    int tile = loc % 9;
    int ty0 = (tile / 3) * 16, tx0 = (tile % 3) * 16;
    int t = threadIdx.x;
    int wave = t >> 6, lane = t & 63;
    int wm = wave & 1, wq = wave >> 1;           // oc-half, row-quad (0..3)
    int l15 = lane & 15, lg = lane >> 4;

    const size_t inb = (size_t)b * PPIX * 128;
    const __hip_bfloat16* wbase = w + (size_t)(wm * 64 + l15) * 128 + lg * 8;

    int sbase[4];
    #pragma unroll
    for (int n = 0; n < 4; ++n) sbase[n] = (wq * 4 + n) * 20 + l15;

    f32x4 acc[4][4] = {};

    // one slice (512 of 1600 16B slots): linear LDS dest, pre-swizzled source
    // (identical involution to R7's verified layout).
    auto stage_part = [&](int buf, int icb2, int part) {
        int sg = part * 512 + t;
        if (sg < 1600) {
            int u = sg >> 3, j = sg & 7;
            int bb2 = j ^ (u & 7);
            int s = (u << 1) | (bb2 >> 2);
            int lg2 = bb2 & 3;
            int ry = s / 20, rx = s % 20;
            const __hip_bfloat16* gp = in + inb + (size_t)((ty0 + ry) * 52 + tx0 + rx) * 128 + icb2 + lg2 * 8;
            char* lp = &lds[buf][sg * 16];
            GLOAD_LDS16(gp, lp);
        }
    };

#define AISSUE(Areg, tap_) do { \
        const __hip_bfloat16* wp = wbase + (size_t)(tap_) * 16384 + icb; \
        Areg[0] = *(const bf16x8*)(wp); \
        Areg[1] = *(const bf16x8*)(wp + 2048); \
        Areg[2] = *(const bf16x8*)(wp + 4096); \
        Areg[3] = *(const bf16x8*)(wp + 6144); \
    } while (0)

#define LDSB(s_) (*(const bf16x8*)(cb + (((s_) >> 1) << 7) + \
        ((((((s_) & 1) << 2) | lg) ^ (((s_) >> 1) & 7)) << 4)))

#define CTAP(Areg, tap_) do { \
        int toff = (tap_) + 15 * ((tap_) / 5); \
        bf16x8 Bc0 = LDSB(sbase[0] + toff); \
        bf16x8 Bc1 = LDSB(sbase[1] + toff); \
        __builtin_amdgcn_s_setprio(1); \
        _Pragma("unroll") \
        for (int n = 0; n < 4; ++n) { \
            bf16x8 Bc2 = Bc1; \
            if (n < 2) Bc2 = LDSB(sbase[n + 2] + toff); \
            acc[0][n] = __builtin_amdgcn_mfma_f32_16x16x32_bf16(Areg[0], Bc0, acc[0][n], 0, 0, 0); \
            acc[1][n] = __builtin_amdgcn_mfma_f32_16x16x32_bf16(Areg[1], Bc0, acc[1][n], 0, 0, 0); \
            acc[2][n] = __builtin_amdgcn_mfma_f32_16x16x32_bf16(Areg[2], Bc0, acc[2][n], 0, 0, 0); \
            acc[3][n] = __builtin_amdgcn_mfma_f32_16x16x32_bf16(Areg[3], Bc0, acc[3][n], 0, 0, 0); \
            Bc0 = Bc1; Bc1 = Bc2; \
        } \
        __builtin_amdgcn_s_setprio(0); \
    } while (0)

    #pragma unroll
    for (int j = 0; j < 4; ++j) stage_part(0, 0, j);
    __syncthreads();

    for (int c = 0; c < 4; ++c) {
        const int icb = c * 32;
        const char* cb = lds[c & 1];
        bf16x8 A0[4], A1[4];
        AISSUE(A0, 0);
        AISSUE(A1, 1);
        __builtin_amdgcn_sched_barrier(0);     // keep A0/A1 issue first
        for (int i = 0; i < 12; ++i) {
            int tp = 2 * i;
            CTAP(A0, tp);
            AISSUE(A0, tp + 2);
            if (c < 3 && i < 4) {
                stage_part((c + 1) & 1, icb + 32, i);
                __builtin_amdgcn_sched_barrier(0);   // pin slice between CTAPs
            }
            CTAP(A1, tp + 1);
            AISSUE(A1, tp + 3);   // over-issues taps 25..27 once; lands in ws slack
        }
        CTAP(A0, 24);
        if (c < 3) __syncthreads();
    }
#undef AISSUE
#undef LDSB
#undef CTAP

    // epilogue: D[row = oc_local = lg*4+reg][col = pix = l15]
    #pragma unroll
    for (int m = 0; m < 4; ++m) {
        int ocm = wm * 64 + m * 16 + lg * 4;
        float bv0 = bias[ocm], bv1 = bias[ocm + 1], bv2 = bias[ocm + 2], bv3 = bias[ocm + 3];
        float ps0 = 0, ps1 = 0, ps2 = 0, ps3 = 0;
        #pragma unroll
        for (int n = 0; n < 4; ++n) {
            float v0 = acc[m][n][0] + bv0, v1 = acc[m][n][1] + bv1;
            float v2 = acc[m][n][2] + bv2, v3 = acc[m][n][3] + bv3;
            ps0 += v0; ps1 += v1; ps2 += v2; ps3 += v3;
            if (LEAKY) {
                v0 = v0 > 0.f ? v0 : 0.01f * v0; v1 = v1 > 0.f ? v1 : 0.01f * v1;
                v2 = v2 > 0.f ? v2 : 0.01f * v2; v3 = v3 > 0.f ? v3 : 0.01f * v3;
            }
            int row = ty0 + wq * 4 + n, col = tx0 + l15;
            size_t off;
            if (PADOUT) off = ((size_t)b * PPIX + (row + 2) * 52 + col + 2) * 128 + ocm;
            else        off = ((size_t)b * PIX + row * 48 + col) * 128 + ocm;
            uint2 pk;
            pk.x = (unsigned)f2b(v0) | ((unsigned)f2b(v1) << 16);
            pk.y = (unsigned)f2b(v2) | ((unsigned)f2b(v3) << 16);
            *(uint2*)(out + off) = pk;
        }
        if (MEAN) {
            #pragma unroll
            for (int mask = 1; mask < 16; mask <<= 1) {
                ps0 += __shfl_xor(ps0, mask);
                ps1 += __shfl_xor(ps1, mask);
                ps2 += __shfl_xor(ps2, mask);
                ps3 += __shfl_xor(ps3, mask);
            }
            if (l15 == 0) {
                atomicAdd(&mean[b * 128 + ocm], ps0);
                atomicAdd(&mean[b * 128 + ocm + 1], ps1);
                atomicAdd(&mean[b * 128 + ocm + 2], ps2);
                atomicAdd(&mean[b * 128 + ocm + 3], ps3);
            }
        }
    }
}

// ---------------- K6: SE gate ----------------
__global__ void k_se(const float* __restrict__ mean, const float* __restrict__ w1,
                     const float* __restrict__ w2, float* __restrict__ s) {
    __shared__ float m[128];
    __shared__ float tt[8];
    int b = blockIdx.x, t = threadIdx.x;
    m[t] = mean[b * RESC + t] * (1.0f / 2304.0f);
    __syncthreads();
    if (t < 8) {
        float a = 0.f;
        for (int i = 0; i < 128; i++) a += w1[t * 128 + i] * m[i];
        tt[t] = a > 0.f ? a : 0.f;
    }
    __syncthreads();
    float a = 0.f;
    #pragma unroll
    for (int r = 0; r < 8; r++) a += w2[t * 8 + r] * tt[r];
    s[b * RESC + t] = 1.f / (1.f + expf(-a));
}

// ---------------- K7: out(NCHW f32) = leaky(y2*s + h), NHWC->NCHW via LDS ----------------
__global__ __launch_bounds__(256) void k_final(const __hip_bfloat16* __restrict__ y2,
                                               const __hip_bfloat16* __restrict__ h,
                                               const float* __restrict__ sg, float* __restrict__ out) {
    __shared__ float sl[128];
    __shared__ float tile[64 * 129];
    int b = blockIdx.y, p0 = blockIdx.x * 64, t = threadIdx.x;
    if (t < 128) sl[t] = sg[b * 128 + t];
    __syncthreads();
    #pragma unroll
    for (int k = 0; k < 4; ++k) {
        int j = t + k * 256;
        int pix = j >> 4, c = j & 15;
        int p = p0 + pix;
        int py = p / 48, px2 = p % 48;
        uint4 yv = *(const uint4*)(y2 + ((size_t)b * PIX + p) * 128 + c * 8);
        uint4 hv = *(const uint4*)(h + ((size_t)b * PPIX + (py + 2) * 52 + px2 + 2) * 128 + c * 8);
        const unsigned short* yp = (const unsigned short*)&yv;
        const unsigned short* hp = (const unsigned short*)&hv;
        #pragma unroll
        for (int jj = 0; jj < 8; ++jj) {
            int oc = c * 8 + jj;
            tile[pix * 129 + oc] = b2f(yp[jj]) * sl[oc] + b2f(hp[jj]);
        }
    }
    __syncthreads();
    int oc = t >> 1, xh = (t & 1) * 32;
    float ov[32];
    #pragma unroll
    for (int i = 0; i < 32; ++i) {
        float v = tile[(xh + i) * 129 + oc];
        ov[i] = v > 0.f ? v : 0.01f * v;
    }
    float* op = out + ((size_t)b * 128 + oc) * PIX + p0 + xh;
    #pragma unroll
    for (int q = 0; q < 8; ++q) ((float4*)op)[q] = *(float4*)&ov[q * 4];
}

extern "C" void kernel_launch(void* const* d_in, const int* in_sizes, int n_in,
                              void* d_out, int out_size, void* d_ws, size_t ws_size,
                              hipStream_t stream) {
    const float* x      = (const float*)d_in[0];
    const float* fc_w   = (const float*)d_in[1];
    const float* fc_b   = (const float*)d_in[2];
    const float* ohw    = (const float*)d_in[3];
    const float* ohb    = (const float*)d_in[4];
    const float* otw    = (const float*)d_in[5];
    const float* otb    = (const float*)d_in[6];
    const float* aw     = (const float*)d_in[7];
    const float* ab     = (const float*)d_in[8];
    const float* c1w    = (const float*)d_in[9];
    const float* c1b    = (const float*)d_in[10];
    const float* r1w    = (const float*)d_in[11];
    const float* r1b    = (const float*)d_in[12];
    const float* r2w    = (const float*)d_in[13];
    const float* r2b    = (const float*)d_in[14];
    const float* se_w1  = (const float*)d_in[15];
    const float* se_w2  = (const float*)d_in[16];

    const size_t padb = (size_t)BB * PPIX * 128 * sizeof(__hip_bfloat16);    // 88.6 MB
    char* ws = (char*)d_ws;
    __hip_bfloat16* h    = (__hip_bfloat16*)ws;  ws += padb;
    __hip_bfloat16* y1   = (__hip_bfloat16*)ws;  ws += padb;
    __hip_bfloat16* y2   = (__hip_bfloat16*)ws;  ws += (size_t)BB * PIX * 128 * sizeof(__hip_bfloat16);
    float* G    = (float*)ws;                    ws += (size_t)PIX * 128 * sizeof(float);
    float* v    = (float*)ws;                    ws += (size_t)BB * 9 * sizeof(float);
    __hip_bfloat16* wb1 = (__hip_bfloat16*)ws;   ws += (size_t)25 * 128 * 128 * sizeof(__hip_bfloat16);
    __hip_bfloat16* wb2 = (__hip_bfloat16*)ws;   ws += (size_t)25 * 128 * 128 * sizeof(__hip_bfloat16);
    ws += 262144;                                // slack for A over-issue reads
    float* mean = (float*)ws;                    ws += (size_t)BB * RESC * sizeof(float);
    float* sgate= (float*)ws;                    ws += (size_t)BB * RESC * sizeof(float);

    k_compute_v<<<1, 128, 0, stream>>>(x, fc_w, fc_b, v);
    k_compute_G<<<9, 256, 0, stream>>>(x, v, ohw, ohb, otw, otb, aw, ab, c1w, c1b, G);
    k_convert_w<<<1600, 256, 0, stream>>>(r1w, r2w, wb1, wb2);
    k_zero_border<<<128, 256, 0, stream>>>(h, y1);
    k_conv1<<<dim3(36, 128), 256, 0, stream>>>(x, c1w, G, h);
    k_conv5_mfma<true, false, true><<<dim3(1152), 512, 0, stream>>>(h, wb1, r1b, y1, nullptr);
    hipMemsetAsync(mean, 0, (size_t)BB * RESC * sizeof(float), stream);
    k_conv5_mfma<false, true, false><<<dim3(1152), 512, 0, stream>>>(y1, wb2, r2b, y2, mean);
    k_se<<<128, 128, 0, stream>>>(mean, se_w1, se_w2, sgate);
    k_final<<<dim3(36, 128), 256, 0, stream>>>(y2, h, sgate, (float*)d_out);
}

// Round 13
// 1234.428 us; speedup vs baseline: 1.2094x; 1.2094x over previous
//
#include <hip/hip_runtime.h>
#include <hip/hip_bf16.h>
#include <cstddef>

#define HH 48
#define WW 48
#define PIX 2304
#define PPIX 2704           // 52*52 padded
#define BB 128
#define RESC 128
#define XCH 33

typedef short bf16x8 __attribute__((ext_vector_type(8)));
typedef float f32x4 __attribute__((ext_vector_type(4)));

static __device__ __forceinline__ float b2f(unsigned short u) {
    unsigned x = ((unsigned)u) << 16;
    return __builtin_bit_cast(float, x);
}
static __device__ __forceinline__ unsigned short f2b(float f) {
    __hip_bfloat16 hb = __float2bfloat16(f);
    return __builtin_bit_cast(unsigned short, hb);
}

#define GLOAD_LDS16(gp, lp) __builtin_amdgcn_global_load_lds( \
    (const __attribute__((address_space(1))) void*)(gp), \
    (__attribute__((address_space(3))) void*)(lp), 16, 0, 0)

// ---------------- K1: one-hot gather -> v[128][9] ----------------
__global__ void k_compute_v(const float* __restrict__ x, const float* __restrict__ fc_w,
                            const float* __restrict__ fc_b, float* __restrict__ v) {
    int b = blockIdx.x * blockDim.x + threadIdx.x;
    if (b >= BB) return;
    const int off[20] = {0,5,12,16,22,25,33,38,42,48,55,58,63,67,73,81,86,93,97,103};
    const float* gi = x + (size_t)b * XCH * PIX;
    int cols[20];
    #pragma unroll
    for (int j = 0; j < 20; j++) cols[j] = off[j] + (int)gi[j];
    #pragma unroll
    for (int e = 0; e < 9; e++) {
        float acc = fc_b[e];
        #pragma unroll
        for (int j = 0; j < 20; j++) acc += fc_w[e * 106 + cols[j]];
        v[b * 9 + e] = acc;
    }
}

// ---------------- K2: per-pixel composite G[p][128oc] fp32 (oc-split, 36 blocks) ----
__global__ __launch_bounds__(256) void k_compute_G(
        const float* __restrict__ x, const float* __restrict__ v,
        const float* __restrict__ ohw, const float* __restrict__ ohb,
        const float* __restrict__ otw, const float* __restrict__ otb,
        const float* __restrict__ aw,  const float* __restrict__ ab,
        const float* __restrict__ c1w, const float* __restrict__ c1b,
        float* __restrict__ G) {
    int t = threadIdx.x;
    int p = blockIdx.x * 64 + (t & 63);
    int og = t >> 6;                         // oc-group: 32 oc each
    if (p >= PIX) return;
    float sv = v[((p / 9) & 127) * 9 + (p % 9)];
    float om[30];
    #pragma unroll
    for (int c2 = 0; c2 < 30; c2++) {
        int tmp = c2 * 24 + p;
        int c = tmp % 30;
        int bb = (c2 * 76 + tmp / 30) & 127;
        om[c2] = x[(size_t)bb * XCH * PIX + 20 + c];
    }
    float v9[9];
    #pragma unroll
    for (int e = 0; e < 9; e++) {
        float srow = 0.f;
        #pragma unroll
        for (int e2 = 0; e2 < 9; e2++) srow += ohw[e * 9 + e2];
        v9[e] = ohb[e] + srow * sv;
    }
    float o30[30];
    #pragma unroll
    for (int c = 0; c < 30; c++) {
        float a = otb[c];
        #pragma unroll
        for (int c2 = 0; c2 < 30; c2++) a += otw[c * 30 + c2] * om[c2];
        o30[c] = a;
    }
    float gi32[32];
    #pragma unroll
    for (int g = 0; g < 32; g++) {
        float a = ab[g];
        #pragma unroll
        for (int e = 0; e < 9; e++) a += aw[g * 39 + e] * v9[e];
        #pragma unroll
        for (int c = 0; c < 30; c++) a += aw[g * 39 + 9 + c] * o30[c];
        gi32[g] = a;
    }
    for (int oc = og * 32; oc < og * 32 + 32; oc++) {
        float a = c1b[oc];
        #pragma unroll
        for (int g = 0; g < 32; g++) a += c1w[oc * 64 + g] * gi32[g];
        G[p * 128 + oc] = a;
    }
}

// ---------------- K2b: weights -> bf16 [tap][oc][ic] ----------------
__global__ void k_convert_w(const float* __restrict__ w1, const float* __restrict__ w2,
                            __hip_bfloat16* __restrict__ wb1, __hip_bfloat16* __restrict__ wb2) {
    int i = blockIdx.x * 256 + threadIdx.x;
    if (i >= 25 * 128 * 128) return;
    int tap = i / 16384, r = i % 16384;
    int oc = r >> 7, ic = r & 127;
    size_t src = (size_t)(oc * 128 + ic) * 25 + tap;
    wb1[i] = __float2bfloat16(w1[src]);
    wb2[i] = __float2bfloat16(w2[src]);
}

// ---------------- K2c: zero borders of the two padded buffers ----------------
__global__ void k_zero_border(__hip_bfloat16* __restrict__ a, __hip_bfloat16* __restrict__ b2) {
    int img = blockIdx.x, t = threadIdx.x;
    for (int j = t; j < 6400; j += 256) {
        int pb = j >> 4, c16 = j & 15;
        int y, x2;
        if (pb < 208) { int q = pb / 52; y = q < 2 ? q : q + 48; x2 = pb % 52; }
        else { int r = pb - 208; y = 2 + (r >> 2); int c = r & 3; x2 = c < 2 ? c : c + 48; }
        size_t off = ((size_t)img * PPIX + y * 52 + x2) * 128 + c16 * 8;
        uint4 z = {0, 0, 0, 0};
        *(uint4*)(a + off) = z;
        *(uint4*)(b2 + off) = z;
    }
}

// ---------------- K3: h_pad[b][52][52][128] = G + W1[:,32:] @ map ----------------
__global__ __launch_bounds__(256) void k_conv1(const float* __restrict__ x, const float* __restrict__ c1w,
                                               const float* __restrict__ G, __hip_bfloat16* __restrict__ h) {
    __shared__ float xm[32][64];
    __shared__ float w1[32][128];
    int b = blockIdx.y, p0 = blockIdx.x * 64;
    int t = threadIdx.x;
    for (int i = t; i < 4096; i += 256) { int m = i >> 7, oc = i & 127; w1[m][oc] = c1w[oc * 64 + 32 + m]; }
    for (int i = t; i < 2048; i += 256) {
        int m = i >> 6, pix = i & 63;
        xm[m][pix] = x[(size_t)b * XCH * PIX + (size_t)(1 + m) * PIX + p0 + pix];
    }
    __syncthreads();
    int pix = t & 63, ocg = t >> 6;
    float acc[32] = {};
    for (int m = 0; m < 32; m++) {
        float xv = xm[m][pix];
        const float4* wr = (const float4*)&w1[m][ocg * 32];
        #pragma unroll
        for (int k4 = 0; k4 < 8; k4++) {
            float4 wv = wr[k4];
            acc[k4 * 4 + 0] += wv.x * xv; acc[k4 * 4 + 1] += wv.y * xv;
            acc[k4 * 4 + 2] += wv.z * xv; acc[k4 * 4 + 3] += wv.w * xv;
        }
    }
    int p = p0 + pix;
    int py = p / 48, px2 = p % 48;
    size_t hb = ((size_t)b * PPIX + (py + 2) * 52 + px2 + 2) * 128 + ocg * 32;
    const float* gp = &G[(size_t)p * 128 + ocg * 32];
    #pragma unroll
    for (int q = 0; q < 4; q++) {
        unsigned short u[8];
        #pragma unroll
        for (int j = 0; j < 8; j++) u[j] = f2b(acc[q * 8 + j] + gp[q * 8 + j]);
        *(uint4*)(&h[hb + q * 8]) = *(uint4*)u;
    }
}

// ---------------- K4/K5: 5x5 conv, implicit GEMM, BARRIER-FREE main loop ----------------
// block: 1 batch, 16x16 spatial, 128 oc, 512 threads = 8 waves.
// Full input tile (20x20 x 128ic = 102.4 KB) staged ONCE into LDS (4 planes of
// 25.6 KB, each with R7's verified involution layout). One __syncthreads total;
// the 100-tap main loop has NO barriers — waves free-run with depth-2 A-prefetch.
// wave (wm: oc-half, wq: row-quad) = 64oc x 64px: acc[4][4] = 64 AGPR (~148 regs).
// Same 1152-block grid + XCD-batch swizzle (L2 attractor inputs unchanged).
template<bool LEAKY, bool MEAN, bool PADOUT>
__global__ __launch_bounds__(512, 2) void k_conv5_mfma(
        const __hip_bfloat16* __restrict__ in,   // [B][52][52][128] padded
        const __hip_bfloat16* __restrict__ w,    // [25][128][128]
        const float* __restrict__ bias,
        __hip_bfloat16* __restrict__ out,
        float* __restrict__ mean) {
    __shared__ __align__(16) char lds[102400];   // 4 planes x 25600 B
    // XCD-batch swizzle: 1152 blocks = 8 XCDs x (16 batches x 9 tiles)
    int bid = blockIdx.x;
    int xcd = bid & 7, loc = bid >> 3;
    int b = xcd * 16 + loc / 9;
    int tile = loc % 9;
    int ty0 = (tile / 3) * 16, tx0 = (tile % 3) * 16;
    int t = threadIdx.x;
    int wave = t >> 6, lane = t & 63;
    int wm = wave & 1, wq = wave >> 1;           // oc-half, row-quad (0..3)
    int l15 = lane & 15, lg = lane >> 4;

    const size_t inb = (size_t)b * PPIX * 128;
    const __hip_bfloat16* wbase = w + (size_t)(wm * 64 + l15) * 128 + lg * 8;

    int sbase[4];
    #pragma unroll
    for (int n = 0; n < 4; ++n) sbase[n] = (wq * 4 + n) * 20 + l15;

    f32x4 acc[4][4] = {};

    // Stage the FULL 128-ic tile: 6400 16B slots = 4 planes x 1600.
    // Within each plane: R7's verified involution (linear LDS dest,
    // pre-swizzled global source). Plane p holds ic [p*32, p*32+32).
    #pragma unroll
    for (int part = 0; part < 13; ++part) {
        int sg = part * 512 + t;
        if (sg < 6400) {
            int plane = sg / 1600, r = sg % 1600;
            int u = r >> 3, j = r & 7;
            int bb2 = j ^ (u & 7);
            int s = (u << 1) | (bb2 >> 2);
            int lg2 = bb2 & 3;
            int ry = s / 20, rx = s % 20;
            const __hip_bfloat16* gp = in + inb + (size_t)((ty0 + ry) * 52 + tx0 + rx) * 128
                                       + plane * 32 + lg2 * 8;
            char* lp = &lds[plane * 25600 + r * 16];
            GLOAD_LDS16(gp, lp);
        }
    }
    __syncthreads();   // the ONLY barrier

#define AISSUE(Areg, tap_) do { \
        const __hip_bfloat16* wp = wbase + (size_t)(tap_) * 16384 + icb; \
        Areg[0] = *(const bf16x8*)(wp); \
        Areg[1] = *(const bf16x8*)(wp + 2048); \
        Areg[2] = *(const bf16x8*)(wp + 4096); \
        Areg[3] = *(const bf16x8*)(wp + 6144); \
    } while (0)

#define LDSB(s_) (*(const bf16x8*)(cb + (((s_) >> 1) << 7) + \
        ((((((s_) & 1) << 2) | lg) ^ (((s_) >> 1) & 7)) << 4)))

#define CTAP(Areg, tap_) do { \
        int toff = (tap_) + 15 * ((tap_) / 5); \
        bf16x8 Bc0 = LDSB(sbase[0] + toff); \
        bf16x8 Bc1 = LDSB(sbase[1] + toff); \
        __builtin_amdgcn_s_setprio(1); \
        _Pragma("unroll") \
        for (int n = 0; n < 4; ++n) { \
            bf16x8 Bc2 = Bc1; \
            if (n < 2) Bc2 = LDSB(sbase[n + 2] + toff); \
            acc[0][n] = __builtin_amdgcn_mfma_f32_16x16x32_bf16(Areg[0], Bc0, acc[0][n], 0, 0, 0); \
            acc[1][n] = __builtin_amdgcn_mfma_f32_16x16x32_bf16(Areg[1], Bc0, acc[1][n], 0, 0, 0); \
            acc[2][n] = __builtin_amdgcn_mfma_f32_16x16x32_bf16(Areg[2], Bc0, acc[2][n], 0, 0, 0); \
            acc[3][n] = __builtin_amdgcn_mfma_f32_16x16x32_bf16(Areg[3], Bc0, acc[3][n], 0, 0, 0); \
            Bc0 = Bc1; Bc1 = Bc2; \
        } \
        __builtin_amdgcn_s_setprio(0); \
    } while (0)

    #pragma unroll 1
    for (int c = 0; c < 4; ++c) {
        const int icb = c * 32;
        const char* cb = lds + c * 25600;
        bf16x8 A0[4], A1[4];
        AISSUE(A0, 0);
        AISSUE(A1, 1);
        __builtin_amdgcn_sched_barrier(0);
        for (int i = 0; i < 12; ++i) {
            int tp = 2 * i;
            CTAP(A0, tp);
            AISSUE(A0, tp + 2);
            CTAP(A1, tp + 1);
            AISSUE(A1, tp + 3);   // over-issues taps 25..27 once; lands in ws slack
        }
        CTAP(A0, 24);
        // no barrier — LDS is read-only from here on
    }
#undef AISSUE
#undef LDSB
#undef CTAP

    // epilogue: D[row = oc_local = lg*4+reg][col = pix = l15]
    #pragma unroll
    for (int m = 0; m < 4; ++m) {
        int ocm = wm * 64 + m * 16 + lg * 4;
        float bv0 = bias[ocm], bv1 = bias[ocm + 1], bv2 = bias[ocm + 2], bv3 = bias[ocm + 3];
        float ps0 = 0, ps1 = 0, ps2 = 0, ps3 = 0;
        #pragma unroll
        for (int n = 0; n < 4; ++n) {
            float v0 = acc[m][n][0] + bv0, v1 = acc[m][n][1] + bv1;
            float v2 = acc[m][n][2] + bv2, v3 = acc[m][n][3] + bv3;
            ps0 += v0; ps1 += v1; ps2 += v2; ps3 += v3;
            if (LEAKY) {
                v0 = v0 > 0.f ? v0 : 0.01f * v0; v1 = v1 > 0.f ? v1 : 0.01f * v1;
                v2 = v2 > 0.f ? v2 : 0.01f * v2; v3 = v3 > 0.f ? v3 : 0.01f * v3;
            }
            int row = ty0 + wq * 4 + n, col = tx0 + l15;
            size_t off;
            if (PADOUT) off = ((size_t)b * PPIX + (row + 2) * 52 + col + 2) * 128 + ocm;
            else        off = ((size_t)b * PIX + row * 48 + col) * 128 + ocm;
            uint2 pk;
            pk.x = (unsigned)f2b(v0) | ((unsigned)f2b(v1) << 16);
            pk.y = (unsigned)f2b(v2) | ((unsigned)f2b(v3) << 16);
            *(uint2*)(out + off) = pk;
        }
        if (MEAN) {
            #pragma unroll
            for (int mask = 1; mask < 16; mask <<= 1) {
                ps0 += __shfl_xor(ps0, mask);
                ps1 += __shfl_xor(ps1, mask);
                ps2 += __shfl_xor(ps2, mask);
                ps3 += __shfl_xor(ps3, mask);
            }
            if (l15 == 0) {
                atomicAdd(&mean[b * 128 + ocm], ps0);
                atomicAdd(&mean[b * 128 + ocm + 1], ps1);
                atomicAdd(&mean[b * 128 + ocm + 2], ps2);
                atomicAdd(&mean[b * 128 + ocm + 3], ps3);
            }
        }
    }
}

// ---------------- K6: SE gate ----------------
__global__ void k_se(const float* __restrict__ mean, const float* __restrict__ w1,
                     const float* __restrict__ w2, float* __restrict__ s) {
    __shared__ float m[128];
    __shared__ float tt[8];
    int b = blockIdx.x, t = threadIdx.x;
    m[t] = mean[b * RESC + t] * (1.0f / 2304.0f);
    __syncthreads();
    if (t < 8) {
        float a = 0.f;
        for (int i = 0; i < 128; i++) a += w1[t * 128 + i] * m[i];
        tt[t] = a > 0.f ? a : 0.f;
    }
    __syncthreads();
    float a = 0.f;
    #pragma unroll
    for (int r = 0; r < 8; r++) a += w2[t * 8 + r] * tt[r];
    s[b * RESC + t] = 1.f / (1.f + expf(-a));
}

// ---------------- K7: out(NCHW f32) = leaky(y2*s + h), NHWC->NCHW via LDS ----------------
__global__ __launch_bounds__(256) void k_final(const __hip_bfloat16* __restrict__ y2,
                                               const __hip_bfloat16* __restrict__ h,
                                               const float* __restrict__ sg, float* __restrict__ out) {
    __shared__ float sl[128];
    __shared__ float tile[64 * 129];
    int b = blockIdx.y, p0 = blockIdx.x * 64, t = threadIdx.x;
    if (t < 128) sl[t] = sg[b * 128 + t];
    __syncthreads();
    #pragma unroll
    for (int k = 0; k < 4; ++k) {
        int j = t + k * 256;
        int pix = j >> 4, c = j & 15;
        int p = p0 + pix;
        int py = p / 48, px2 = p % 48;
        uint4 yv = *(const uint4*)(y2 + ((size_t)b * PIX + p) * 128 + c * 8);
        uint4 hv = *(const uint4*)(h + ((size_t)b * PPIX + (py + 2) * 52 + px2 + 2) * 128 + c * 8);
        const unsigned short* yp = (const unsigned short*)&yv;
        const unsigned short* hp = (const unsigned short*)&hv;
        #pragma unroll
        for (int jj = 0; jj < 8; ++jj) {
            int oc = c * 8 + jj;
            tile[pix * 129 + oc] = b2f(yp[jj]) * sl[oc] + b2f(hp[jj]);
        }
    }
    __syncthreads();
    int oc = t >> 1, xh = (t & 1) * 32;
    float ov[32];
    #pragma unroll
    for (int i = 0; i < 32; ++i) {
        float v = tile[(xh + i) * 129 + oc];
        ov[i] = v > 0.f ? v : 0.01f * v;
    }
    float* op = out + ((size_t)b * 128 + oc) * PIX + p0 + xh;
    #pragma unroll
    for (int q = 0; q < 8; ++q) ((float4*)op)[q] = *(float4*)&ov[q * 4];
}

extern "C" void kernel_launch(void* const* d_in, const int* in_sizes, int n_in,
                              void* d_out, int out_size, void* d_ws, size_t ws_size,
                              hipStream_t stream) {
    const float* x      = (const float*)d_in[0];
    const float* fc_w   = (const float*)d_in[1];
    const float* fc_b   = (const float*)d_in[2];
    const float* ohw    = (const float*)d_in[3];
    const float* ohb    = (const float*)d_in[4];
    const float* otw    = (const float*)d_in[5];
    const float* otb    = (const float*)d_in[6];
    const float* aw     = (const float*)d_in[7];
    const float* ab     = (const float*)d_in[8];
    const float* c1w    = (const float*)d_in[9];
    const float* c1b    = (const float*)d_in[10];
    const float* r1w    = (const float*)d_in[11];
    const float* r1b    = (const float*)d_in[12];
    const float* r2w    = (const float*)d_in[13];
    const float* r2b    = (const float*)d_in[14];
    const float* se_w1  = (const float*)d_in[15];
    const float* se_w2  = (const float*)d_in[16];

    const size_t padb = (size_t)BB * PPIX * 128 * sizeof(__hip_bfloat16);    // 88.6 MB
    char* ws = (char*)d_ws;
    __hip_bfloat16* h    = (__hip_bfloat16*)ws;  ws += padb;
    __hip_bfloat16* y1   = (__hip_bfloat16*)ws;  ws += padb;
    __hip_bfloat16* y2   = (__hip_bfloat16*)ws;  ws += (size_t)BB * PIX * 128 * sizeof(__hip_bfloat16);
    float* G    = (float*)ws;                    ws += (size_t)PIX * 128 * sizeof(float);
    float* v    = (float*)ws;                    ws += (size_t)BB * 9 * sizeof(float);
    __hip_bfloat16* wb1 = (__hip_bfloat16*)ws;   ws += (size_t)25 * 128 * 128 * sizeof(__hip_bfloat16);
    __hip_bfloat16* wb2 = (__hip_bfloat16*)ws;   ws += (size_t)25 * 128 * 128 * sizeof(__hip_bfloat16);
    ws += 262144;                                // slack for A over-issue reads
    float* mean = (float*)ws;                    ws += (size_t)BB * RESC * sizeof(float);
    float* sgate= (float*)ws;                    ws += (size_t)BB * RESC * sizeof(float);

    k_compute_v<<<1, 128, 0, stream>>>(x, fc_w, fc_b, v);
    k_compute_G<<<36, 256, 0, stream>>>(x, v, ohw, ohb, otw, otb, aw, ab, c1w, c1b, G);
    k_convert_w<<<1600, 256, 0, stream>>>(r1w, r2w, wb1, wb2);
    k_zero_border<<<128, 256, 0, stream>>>(h, y1);
    k_conv1<<<dim3(36, 128), 256, 0, stream>>>(x, c1w, G, h);
    k_conv5_mfma<true, false, true><<<dim3(1152), 512, 0, stream>>>(h, wb1, r1b, y1, nullptr);
    hipMemsetAsync(mean, 0, (size_t)BB * RESC * sizeof(float), stream);
    k_conv5_mfma<false, true, false><<<dim3(1152), 512, 0, stream>>>(y1, wb2, r2b, y2, mean);
    k_se<<<128, 128, 0, stream>>>(mean, se_w1, se_w2, sgate);
    k_final<<<dim3(36, 128), 256, 0, stream>>>(y2, h, sgate, (float*)d_out);
}

// Round 14
// 726.247 us; speedup vs baseline: 2.0557x; 1.6997x over previous
//
#include <hip/hip_runtime.h>
#include <hip/hip_bf16.h>
#include <cstddef>

#define HH 48
#define WW 48
#define PIX 2304
#define PPIX 2704           // 52*52 padded
#define BB 128
#define RESC 128
#define XCH 33

typedef short bf16x8 __attribute__((ext_vector_type(8)));
typedef float f32x4 __attribute__((ext_vector_type(4)));

static __device__ __forceinline__ float b2f(unsigned short u) {
    unsigned x = ((unsigned)u) << 16;
    return __builtin_bit_cast(float, x);
}
static __device__ __forceinline__ unsigned short f2b(float f) {
    __hip_bfloat16 hb = __float2bfloat16(f);
    return __builtin_bit_cast(unsigned short, hb);
}

#define GLOAD_LDS16(gp, lp) __builtin_amdgcn_global_load_lds( \
    (const __attribute__((address_space(1))) void*)(gp), \
    (__attribute__((address_space(3))) void*)(lp), 16, 0, 0)

// ---------------- K2: per-pixel composite G[p][128oc] fp32 (v fused in-block) ----
__global__ __launch_bounds__(256) void k_compute_G(
        const float* __restrict__ x, const float* __restrict__ fc_w,
        const float* __restrict__ fc_b,
        const float* __restrict__ ohw, const float* __restrict__ ohb,
        const float* __restrict__ otw, const float* __restrict__ otb,
        const float* __restrict__ aw,  const float* __restrict__ ab,
        const float* __restrict__ c1w, const float* __restrict__ c1b,
        float* __restrict__ G) {
    __shared__ float vsh[128][9];
    int t = threadIdx.x;
    // per-block redundant v compute (cheap): thread tid<128 -> batch tid
    if (t < 128) {
        const int off[20] = {0,5,12,16,22,25,33,38,42,48,55,58,63,67,73,81,86,93,97,103};
        const float* gi = x + (size_t)t * XCH * PIX;
        int cols[20];
        #pragma unroll
        for (int j = 0; j < 20; j++) cols[j] = off[j] + (int)gi[j];
        #pragma unroll
        for (int e = 0; e < 9; e++) {
            float acc = fc_b[e];
            #pragma unroll
            for (int j = 0; j < 20; j++) acc += fc_w[e * 106 + cols[j]];
            vsh[t][e] = acc;
        }
    }
    __syncthreads();
    int p = blockIdx.x * 64 + (t & 63);
    int og = t >> 6;                         // oc-group: 32 oc each
    if (p >= PIX) return;
    float sv = vsh[(p / 9) & 127][p % 9];
    float om[30];
    #pragma unroll
    for (int c2 = 0; c2 < 30; c2++) {
        int tmp = c2 * 24 + p;
        int c = tmp % 30;
        int bb = (c2 * 76 + tmp / 30) & 127;
        om[c2] = x[(size_t)bb * XCH * PIX + 20 + c];
    }
    float v9[9];
    #pragma unroll
    for (int e = 0; e < 9; e++) {
        float srow = 0.f;
        #pragma unroll
        for (int e2 = 0; e2 < 9; e2++) srow += ohw[e * 9 + e2];
        v9[e] = ohb[e] + srow * sv;
    }
    float o30[30];
    #pragma unroll
    for (int c = 0; c < 30; c++) {
        float a = otb[c];
        #pragma unroll
        for (int c2 = 0; c2 < 30; c2++) a += otw[c * 30 + c2] * om[c2];
        o30[c] = a;
    }
    float gi32[32];
    #pragma unroll
    for (int g = 0; g < 32; g++) {
        float a = ab[g];
        #pragma unroll
        for (int e = 0; e < 9; e++) a += aw[g * 39 + e] * v9[e];
        #pragma unroll
        for (int c = 0; c < 30; c++) a += aw[g * 39 + 9 + c] * o30[c];
        gi32[g] = a;
    }
    for (int oc = og * 32; oc < og * 32 + 32; oc++) {
        float a = c1b[oc];
        #pragma unroll
        for (int g = 0; g < 32; g++) a += c1w[oc * 64 + g] * gi32[g];
        G[p * 128 + oc] = a;
    }
}

// ---------------- K2b: weights -> bf16 [tap][oc][ic] ----------------
__global__ void k_convert_w(const float* __restrict__ w1, const float* __restrict__ w2,
                            __hip_bfloat16* __restrict__ wb1, __hip_bfloat16* __restrict__ wb2) {
    int i = blockIdx.x * 256 + threadIdx.x;
    if (i >= 25 * 128 * 128) return;
    int tap = i / 16384, r = i % 16384;
    int oc = r >> 7, ic = r & 127;
    size_t src = (size_t)(oc * 128 + ic) * 25 + tap;
    wb1[i] = __float2bfloat16(w1[src]);
    wb2[i] = __float2bfloat16(w2[src]);
}

// ---------------- K2c: zero borders of padded buffers + zero mean ----------------
__global__ void k_zero_border(__hip_bfloat16* __restrict__ a, __hip_bfloat16* __restrict__ b2,
                              float* __restrict__ mean) {
    int img = blockIdx.x, t = threadIdx.x;
    if (t < 128) mean[img * 128 + t] = 0.f;
    for (int j = t; j < 6400; j += 256) {
        int pb = j >> 4, c16 = j & 15;
        int y, x2;
        if (pb < 208) { int q = pb / 52; y = q < 2 ? q : q + 48; x2 = pb % 52; }
        else { int r = pb - 208; y = 2 + (r >> 2); int c = r & 3; x2 = c < 2 ? c : c + 48; }
        size_t off = ((size_t)img * PPIX + y * 52 + x2) * 128 + c16 * 8;
        uint4 z = {0, 0, 0, 0};
        *(uint4*)(a + off) = z;
        *(uint4*)(b2 + off) = z;
    }
}

// ---------------- K3: h_pad = G + W1[:,32:] @ map, bf16 MFMA ----------------
// block: 1 batch, 64 px, 128 oc; 4 waves, wave = 32 oc x 64 px.
// K = 32 (map channels) = one 16x16x32 k-step. A/B/C lane maps identical to conv5
// (verified): A lane(row=l15=oc, k=lg*8+j); B lane(col=l15=px, k=lg*8+j);
// D col=l15=px, row(oc within 16) = lg*4 + reg.
__global__ __launch_bounds__(256) void k_conv1(const float* __restrict__ x, const float* __restrict__ c1w,
                                               const float* __restrict__ G, __hip_bfloat16* __restrict__ h) {
    int b = blockIdx.y, p0 = blockIdx.x * 64;
    int t = threadIdx.x, wave = t >> 6, lane = t & 63;
    int l15 = lane & 15, lg = lane >> 4;

    // A: 2 m-tiles of 16 oc (wave covers 32 oc)
    bf16x8 a[2];
    #pragma unroll
    for (int m = 0; m < 2; ++m) {
        int oc = wave * 32 + m * 16 + l15;
        const float* wp = c1w + oc * 64 + 32 + lg * 8;
        float4 f0 = *(const float4*)wp;
        float4 f1 = *(const float4*)(wp + 4);
        unsigned short u[8] = { f2b(f0.x), f2b(f0.y), f2b(f0.z), f2b(f0.w),
                                f2b(f1.x), f2b(f1.y), f2b(f1.z), f2b(f1.w) };
        a[m] = __builtin_bit_cast(bf16x8, *(uint4*)u);
    }

    f32x4 acc[2][4] = {};
    #pragma unroll
    for (int n = 0; n < 4; ++n) {
        int p = p0 + n * 16 + l15;
        unsigned short ub[8];
        #pragma unroll
        for (int j = 0; j < 8; ++j)
            ub[j] = f2b(x[((size_t)b * XCH + 1 + lg * 8 + j) * PIX + p]);
        bf16x8 Bv = __builtin_bit_cast(bf16x8, *(uint4*)ub);
        acc[0][n] = __builtin_amdgcn_mfma_f32_16x16x32_bf16(a[0], Bv, acc[0][n], 0, 0, 0);
        acc[1][n] = __builtin_amdgcn_mfma_f32_16x16x32_bf16(a[1], Bv, acc[1][n], 0, 0, 0);
    }

    #pragma unroll
    for (int m = 0; m < 2; ++m) {
        #pragma unroll
        for (int n = 0; n < 4; ++n) {
            int oc4 = wave * 32 + m * 16 + lg * 4;
            int p = p0 + n * 16 + l15;
            int py = p / 48, px2 = p % 48;
            float4 g = *(const float4*)&G[(size_t)p * 128 + oc4];
            float v0 = acc[m][n][0] + g.x, v1 = acc[m][n][1] + g.y;
            float v2 = acc[m][n][2] + g.z, v3 = acc[m][n][3] + g.w;
            uint2 pk;
            pk.x = (unsigned)f2b(v0) | ((unsigned)f2b(v1) << 16);
            pk.y = (unsigned)f2b(v2) | ((unsigned)f2b(v3) << 16);
            *(uint2*)(&h[((size_t)b * PPIX + (py + 2) * 52 + px2 + 2) * 128 + oc4]) = pk;
        }
    }
}

// ---------------- K4/K5: 5x5 conv, implicit GEMM (verified R7/R10 config) ----
// block: 1 batch, 16x16 spatial, 128 oc, 4 waves (wm: oc-half, wn: row-half).
// wave = 64oc x 128px, acc[4][8] = 128 AGPR. 4 chunks of 32 ic, LDS dbuf.
// Depth-2 A-prefetch; 7-slice stage interleave; XCD-batch swizzle.
template<bool LEAKY, bool MEAN, bool PADOUT>
__global__ __launch_bounds__(256, 2) void k_conv5_mfma(
        const __hip_bfloat16* __restrict__ in,   // [B][52][52][128] padded
        const __hip_bfloat16* __restrict__ w,    // [25][128][128]
        const float* __restrict__ bias,
        __hip_bfloat16* __restrict__ out,
        float* __restrict__ mean) {
    __shared__ __align__(16) char lds[2][25600];
    // XCD-batch swizzle: 1152 blocks = 8 XCDs x (16 batches x 9 tiles)
    int bid = blockIdx.x;
    int xcd = bid & 7, loc = bid >> 3;
    int b = xcd * 16 + loc / 9;
    int tile = loc % 9;
    int ty0 = (tile / 3) * 16, tx0 = (tile % 3) * 16;
    int t = threadIdx.x;
    int wave = t >> 6, lane = t & 63;
    int wm = wave & 1, wn = wave >> 1;
    int l15 = lane & 15, lg = lane >> 4;

    const size_t inb = (size_t)b * PPIX * 128;
    const __hip_bfloat16* wbase = w + (size_t)(wm * 64 + l15) * 128 + lg * 8;

    int sbase[8];
    #pragma unroll
    for (int n = 0; n < 8; ++n) sbase[n] = (wn * 8 + n) * 20 + l15;

    f32x4 acc[4][8] = {};

    auto stage_part = [&](int buf, int icb2, int part) {
        int sg = part * 256 + t;
        if (sg < 1600) {
            int u = sg >> 3, j = sg & 7;
            int bb2 = j ^ (u & 7);
            int s = (u << 1) | (bb2 >> 2);
            int lg2 = bb2 & 3;
            int ry = s / 20, rx = s % 20;
            const __hip_bfloat16* gp = in + inb + (size_t)((ty0 + ry) * 52 + tx0 + rx) * 128 + icb2 + lg2 * 8;
            char* lp = &lds[buf][sg * 16];
            GLOAD_LDS16(gp, lp);
        }
    };

#define AISSUE(Areg, tap_) do { \
        const __hip_bfloat16* wp = wbase + (size_t)(tap_) * 16384 + icb; \
        Areg[0] = *(const bf16x8*)(wp); \
        Areg[1] = *(const bf16x8*)(wp + 2048); \
        Areg[2] = *(const bf16x8*)(wp + 4096); \
        Areg[3] = *(const bf16x8*)(wp + 6144); \
    } while (0)

#define LDSB(s_) (*(const bf16x8*)(cb + (((s_) >> 1) << 7) + \
        ((((((s_) & 1) << 2) | lg) ^ (((s_) >> 1) & 7)) << 4)))

#define CTAP(Areg, tap_) do { \
        int toff = (tap_) + 15 * ((tap_) / 5); \
        bf16x8 Bc0 = LDSB(sbase[0] + toff); \
        bf16x8 Bc1 = LDSB(sbase[1] + toff); \
        __builtin_amdgcn_s_setprio(1); \
        _Pragma("unroll") \
        for (int n = 0; n < 8; ++n) { \
            bf16x8 Bc2 = Bc1; \
            if (n < 6) Bc2 = LDSB(sbase[n + 2] + toff); \
            acc[0][n] = __builtin_amdgcn_mfma_f32_16x16x32_bf16(Areg[0], Bc0, acc[0][n], 0, 0, 0); \
            acc[1][n] = __builtin_amdgcn_mfma_f32_16x16x32_bf16(Areg[1], Bc0, acc[1][n], 0, 0, 0); \
            acc[2][n] = __builtin_amdgcn_mfma_f32_16x16x32_bf16(Areg[2], Bc0, acc[2][n], 0, 0, 0); \
            acc[3][n] = __builtin_amdgcn_mfma_f32_16x16x32_bf16(Areg[3], Bc0, acc[3][n], 0, 0, 0); \
            Bc0 = Bc1; Bc1 = Bc2; \
        } \
        __builtin_amdgcn_s_setprio(0); \
    } while (0)

    #pragma unroll
    for (int j = 0; j < 7; ++j) stage_part(0, 0, j);
    __syncthreads();

    for (int c = 0; c < 4; ++c) {
        const int icb = c * 32;
        const char* cb = lds[c & 1];
        bf16x8 A0[4], A1[4];
        AISSUE(A0, 0);
        AISSUE(A1, 1);
        __builtin_amdgcn_sched_barrier(0);     // keep A0/A1 issue first
        for (int i = 0; i < 12; ++i) {
            int tp = 2 * i;
            CTAP(A0, tp);
            AISSUE(A0, tp + 2);
            if (c < 3 && i < 7) {
                stage_part((c + 1) & 1, icb + 32, i);
                __builtin_amdgcn_sched_barrier(0);   // pin slice between CTAPs
            }
            CTAP(A1, tp + 1);
            AISSUE(A1, tp + 3);   // over-issues taps 25..27 once; lands in ws slack
        }
        CTAP(A0, 24);
        if (c < 3) __syncthreads();
    }
#undef AISSUE
#undef LDSB
#undef CTAP

    // epilogue: D[row = oc_local = lg*4+reg][col = pix = l15]
    #pragma unroll
    for (int m = 0; m < 4; ++m) {
        int ocm = wm * 64 + m * 16 + lg * 4;
        float bv0 = bias[ocm], bv1 = bias[ocm + 1], bv2 = bias[ocm + 2], bv3 = bias[ocm + 3];
        float ps0 = 0, ps1 = 0, ps2 = 0, ps3 = 0;
        #pragma unroll
        for (int n = 0; n < 8; ++n) {
            float v0 = acc[m][n][0] + bv0, v1 = acc[m][n][1] + bv1;
            float v2 = acc[m][n][2] + bv2, v3 = acc[m][n][3] + bv3;
            ps0 += v0; ps1 += v1; ps2 += v2; ps3 += v3;
            if (LEAKY) {
                v0 = v0 > 0.f ? v0 : 0.01f * v0; v1 = v1 > 0.f ? v1 : 0.01f * v1;
                v2 = v2 > 0.f ? v2 : 0.01f * v2; v3 = v3 > 0.f ? v3 : 0.01f * v3;
            }
            int row = ty0 + wn * 8 + n, col = tx0 + l15;
            size_t off;
            if (PADOUT) off = ((size_t)b * PPIX + (row + 2) * 52 + col + 2) * 128 + ocm;
            else        off = ((size_t)b * PIX + row * 48 + col) * 128 + ocm;
            uint2 pk;
            pk.x = (unsigned)f2b(v0) | ((unsigned)f2b(v1) << 16);
            pk.y = (unsigned)f2b(v2) | ((unsigned)f2b(v3) << 16);
            *(uint2*)(out + off) = pk;
        }
        if (MEAN) {
            #pragma unroll
            for (int mask = 1; mask < 16; mask <<= 1) {
                ps0 += __shfl_xor(ps0, mask);
                ps1 += __shfl_xor(ps1, mask);
                ps2 += __shfl_xor(ps2, mask);
                ps3 += __shfl_xor(ps3, mask);
            }
            if (l15 == 0) {
                atomicAdd(&mean[b * 128 + ocm], ps0);
                atomicAdd(&mean[b * 128 + ocm + 1], ps1);
                atomicAdd(&mean[b * 128 + ocm + 2], ps2);
                atomicAdd(&mean[b * 128 + ocm + 3], ps3);
            }
        }
    }
}

// ---------------- K6: SE gate ----------------
__global__ void k_se(const float* __restrict__ mean, const float* __restrict__ w1,
                     const float* __restrict__ w2, float* __restrict__ s) {
    __shared__ float m[128];
    __shared__ float tt[8];
    int b = blockIdx.x, t = threadIdx.x;
    m[t] = mean[b * RESC + t] * (1.0f / 2304.0f);
    __syncthreads();
    if (t < 8) {
        float a = 0.f;
        for (int i = 0; i < 128; i++) a += w1[t * 128 + i] * m[i];
        tt[t] = a > 0.f ? a : 0.f;
    }
    __syncthreads();
    float a = 0.f;
    #pragma unroll
    for (int r = 0; r < 8; r++) a += w2[t * 8 + r] * tt[r];
    s[b * RESC + t] = 1.f / (1.f + expf(-a));
}

// ---------------- K7: out(NCHW f32) = leaky(y2*s + h), NHWC->NCHW via LDS ----------------
__global__ __launch_bounds__(256) void k_final(const __hip_bfloat16* __restrict__ y2,
                                               const __hip_bfloat16* __restrict__ h,
                                               const float* __restrict__ sg, float* __restrict__ out) {
    __shared__ float sl[128];
    __shared__ float tile[64 * 129];
    int b = blockIdx.y, p0 = blockIdx.x * 64, t = threadIdx.x;
    if (t < 128) sl[t] = sg[b * 128 + t];
    __syncthreads();
    #pragma unroll
    for (int k = 0; k < 4; ++k) {
        int j = t + k * 256;
        int pix = j >> 4, c = j & 15;
        int p = p0 + pix;
        int py = p / 48, px2 = p % 48;
        uint4 yv = *(const uint4*)(y2 + ((size_t)b * PIX + p) * 128 + c * 8);
        uint4 hv = *(const uint4*)(h + ((size_t)b * PPIX + (py + 2) * 52 + px2 + 2) * 128 + c * 8);
        const unsigned short* yp = (const unsigned short*)&yv;
        const unsigned short* hp = (const unsigned short*)&hv;
        #pragma unroll
        for (int jj = 0; jj < 8; ++jj) {
            int oc = c * 8 + jj;
            tile[pix * 129 + oc] = b2f(yp[jj]) * sl[oc] + b2f(hp[jj]);
        }
    }
    __syncthreads();
    int oc = t >> 1, xh = (t & 1) * 32;
    float ov[32];
    #pragma unroll
    for (int i = 0; i < 32; ++i) {
        float v = tile[(xh + i) * 129 + oc];
        ov[i] = v > 0.f ? v : 0.01f * v;
    }
    float* op = out + ((size_t)b * 128 + oc) * PIX + p0 + xh;
    #pragma unroll
    for (int q = 0; q < 8; ++q) ((float4*)op)[q] = *(float4*)&ov[q * 4];
}

extern "C" void kernel_launch(void* const* d_in, const int* in_sizes, int n_in,
                              void* d_out, int out_size, void* d_ws, size_t ws_size,
                              hipStream_t stream) {
    const float* x      = (const float*)d_in[0];
    const float* fc_w   = (const float*)d_in[1];
    const float* fc_b   = (const float*)d_in[2];
    const float* ohw    = (const float*)d_in[3];
    const float* ohb    = (const float*)d_in[4];
    const float* otw    = (const float*)d_in[5];
    const float* otb    = (const float*)d_in[6];
    const float* aw     = (const float*)d_in[7];
    const float* ab     = (const float*)d_in[8];
    const float* c1w    = (const float*)d_in[9];
    const float* c1b    = (const float*)d_in[10];
    const float* r1w    = (const float*)d_in[11];
    const float* r1b    = (const float*)d_in[12];
    const float* r2w    = (const float*)d_in[13];
    const float* r2b    = (const float*)d_in[14];
    const float* se_w1  = (const float*)d_in[15];
    const float* se_w2  = (const float*)d_in[16];

    const size_t padb = (size_t)BB * PPIX * 128 * sizeof(__hip_bfloat16);    // 88.6 MB
    char* ws = (char*)d_ws;
    __hip_bfloat16* h    = (__hip_bfloat16*)ws;  ws += padb;
    __hip_bfloat16* y1   = (__hip_bfloat16*)ws;  ws += padb;
    __hip_bfloat16* y2   = (__hip_bfloat16*)ws;  ws += (size_t)BB * PIX * 128 * sizeof(__hip_bfloat16);
    float* G    = (float*)ws;                    ws += (size_t)PIX * 128 * sizeof(float);
    __hip_bfloat16* wb1 = (__hip_bfloat16*)ws;   ws += (size_t)25 * 128 * 128 * sizeof(__hip_bfloat16);
    __hip_bfloat16* wb2 = (__hip_bfloat16*)ws;   ws += (size_t)25 * 128 * 128 * sizeof(__hip_bfloat16);
    ws += 262144;                                // slack for A over-issue reads
    float* mean = (float*)ws;                    ws += (size_t)BB * RESC * sizeof(float);
    float* sgate= (float*)ws;                    ws += (size_t)BB * RESC * sizeof(float);

    k_compute_G<<<36, 256, 0, stream>>>(x, fc_w, fc_b, ohw, ohb, otw, otb, aw, ab, c1w, c1b, G);
    k_convert_w<<<1600, 256, 0, stream>>>(r1w, r2w, wb1, wb2);
    k_zero_border<<<128, 256, 0, stream>>>(h, y1, mean);
    k_conv1<<<dim3(36, 128), 256, 0, stream>>>(x, c1w, G, h);
    k_conv5_mfma<true, false, true><<<dim3(1152), 256, 0, stream>>>(h, wb1, r1b, y1, nullptr);
    k_conv5_mfma<false, true, false><<<dim3(1152), 256, 0, stream>>>(y1, wb2, r2b, y2, mean);
    k_se<<<128, 128, 0, stream>>>(mean, se_w1, se_w2, sgate);
    k_final<<<dim3(36, 128), 256, 0, stream>>>(y2, h, sgate, (float*)d_out);
}